// Round 16
// baseline (127.595 us; speedup 1.0000x reference)
//
#include <hip/hip_runtime.h>

typedef float  f32x4  __attribute__((ext_vector_type(4)));
typedef __bf16 bf16x8 __attribute__((ext_vector_type(8)));
typedef __bf16 bf16x2 __attribute__((ext_vector_type(2)));
typedef short  s16x8  __attribute__((ext_vector_type(8)));
typedef unsigned u32x4 __attribute__((ext_vector_type(4)));

static __device__ __forceinline__ unsigned short f2bf(float f) {
  unsigned u = __builtin_bit_cast(unsigned, f);
  u += 0x7FFFu + ((u >> 16) & 1u);          // RNE
  return (unsigned short)(u >> 16);
}

// native pack: compiler emits v_cvt_pk_bf16_f32 (RNE, same numerics as f2bf)
static __device__ __forceinline__ unsigned pk2(float a, float b) {
  bf16x2 v = { (__bf16)a, (__bf16)b };
  return __builtin_bit_cast(unsigned, v);
}

static __device__ __forceinline__ f32x4 mfma16(s16x8 a, s16x8 b, f32x4 c) {
  return __builtin_amdgcn_mfma_f32_16x16x32_bf16(
      __builtin_bit_cast(bf16x8, a), __builtin_bit_cast(bf16x8, b), c, 0, 0, 0);
}

static __device__ __forceinline__ void gll16(const void* g, void* lds) {
  __builtin_amdgcn_global_load_lds(
      (const __attribute__((address_space(1))) unsigned int*)g,
      (__attribute__((address_space(3))) unsigned int*)lds, 16, 0, 0);
}

// ---------------------------------------------------------------------------
// K0: x[B,C,H,W] fp32 -> xb[m][c] bf16 (window-shifted token order),
// coalesced row reads + LDS transpose.
__global__ __launch_bounds__(256) void k_conv_x(const float* __restrict__ x,
                                                unsigned short* __restrict__ xb) {
  __shared__ __align__(16) unsigned short L[512 * 40];
  int bid = blockIdx.x;
  int cchunk = bid & 7, h2 = (bid >> 3) & 1, wy = (bid >> 4) & 15, b = bid >> 8;
  int t = threadIdx.x;
  int cpair = t >> 7, slot = t & 127, lr = slot >> 5, lp = slot & 31;
  int y = (wy * 8 + h2 * 4 + lr + 4) & 127;
  const float* row0 = x + ((size_t)b << 22) + (y << 7);
  int cbase = cchunk * 32;

  for (int it = 0; it < 8; ++it) {
    int cL0 = it * 4 + cpair * 2;
    const float* pa = row0 + ((size_t)(cbase + cL0) << 14) + lp * 4;
    f32x4 a  = *reinterpret_cast<const f32x4*>(pa);
    f32x4 c4 = *reinterpret_cast<const f32x4*>(pa + 16384);
#pragma unroll
    for (int i = 0; i < 4; ++i) {
      int xc = lp * 4 + i;
      int xp = (xc - 4) & 127;
      int wx = xp >> 3, ix = xp & 7;
      int sg = lr * 128 + ix * 16 + wx;
      unsigned pk = (unsigned)f2bf(a[i]) | ((unsigned)f2bf(c4[i]) << 16);
      *reinterpret_cast<unsigned*>(&L[sg * 40 + cL0]) = pk;
    }
  }
  __syncthreads();

  size_t M0 = ((size_t)((b * 16 + wy) * 16)) * 64 + h2 * 32;
  for (int pass = 0; pass < 8; ++pass) {
    int tk = pass * 64 + (t >> 2), p = t & 3;
    int wx = tk >> 5, lr2 = (tk >> 3) & 3, ix = tk & 7;
    int sg = lr2 * 128 + ix * 16 + wx;
    uint4 v = *reinterpret_cast<const uint4*>(&L[sg * 40 + p * 8]);
    size_t m = M0 + (size_t)wx * 64 + lr2 * 8 + ix;
    *reinterpret_cast<uint4*>(&xb[m * 256 + cbase + p * 8]) = v;
  }
}

// ---------------------------------------------------------------------------
// K0b: weight transposes -> K-minor bf16.
__global__ __launch_bounds__(256) void k_conv_w(const float* __restrict__ wqkv,
                                                const float* __restrict__ wout,
                                                unsigned short* __restrict__ wqkvT,
                                                unsigned short* __restrict__ woutT) {
  int j = blockIdx.x, c = threadIdx.x;
  if (j < 768) wqkvT[j * 256 + c] = f2bf(wqkv[c * 768 + j]);
  else { int jj = j - 768; woutT[jj * 256 + c] = f2bf(wout[c * 256 + jj]); }
}

// ---------------------------------------------------------------------------
// K0c: expand relative-position bias table -> bmat[h][s][t] f32 (128 KB).
__global__ __launch_bounds__(256) void k_bias(const float* __restrict__ btab,
                                              float* __restrict__ bmat) {
  int i = blockIdx.x * 256 + threadIdx.x;   // [h][s][t]
  int t = i & 63, s = (i >> 6) & 63, h = i >> 12;
  int idx = ((s >> 3) - (t >> 3) + 7) * 15 + ((s & 7) - (t & 7) + 7);
  bmat[i] = btab[idx * 8 + h];
}

// ---------------------------------------------------------------------------
// K1 fused (R10 structure, launch_bounds midpoint): QKV projection +
// attention + output projection, one block per window (8 waves = 8 heads,
// 512 threads). 32 KB LDS holds A, then O (overlay).
// (512,3): 170 total regs/wave — the unexplored midpoint between R10's
// (512,4)=128 regs (spills, 3 w/EU, 111 us) and R11's (512,2)=256 regs
// (no spill, ~2 w/EU, 112-116 us). Live set ~150 fits 170 -> expect
// spill-free AND 3 w/EU.
__global__ __launch_bounds__(512, 3) void k_fused(const unsigned short* __restrict__ xb,
                                                  const unsigned short* __restrict__ wT,
                                                  const unsigned short* __restrict__ woT,
                                                  const float* __restrict__ bqkv,
                                                  const float* __restrict__ bmat,
                                                  const float* __restrict__ bout,
                                                  float* __restrict__ out) {
  __shared__ __align__(16) unsigned char smA[32768];
  int lane = threadIdx.x & 63, w = threadIdx.x >> 6;
  int bid = blockIdx.x;
  int win = (bid & 7) * 128 + (bid >> 3);   // XCD-bijective swizzle (1024 % 8 == 0)
  int h = w;
  int g = lane >> 4, l15 = lane & 15;
  int m0 = win * 64;
  const float scale = 0.17677669529663687f; // 1/sqrt(32)

  // ---- stage A (64 rows x 256 cols bf16) to LDS, 4 gll16 per wave ----
#pragma unroll
  for (int i = 0; i < 4; ++i) {
    int inst = w * 4 + i;                    // wave-uniform 0..31
    int row = inst * 2 + (lane >> 5);
    int sg = (lane & 31) ^ (row & 7);
    gll16(xb + (size_t)(m0 + row) * 256 + sg * 8, smA + inst * 1024);
  }
  __syncthreads();

  const unsigned short* Wq = wT + (size_t)(h * 32 + l15) * 256 + g * 8;
  const unsigned short* Wk = Wq + 65536;    // +256 rows
  const unsigned short* Wv = Wk + 65536;

  // ======== pass 1: Q,K accumulation (64 AGPR) ========
  f32x4 aQ[2][4], aK[2][4];
#pragma unroll
  for (int jt = 0; jt < 2; ++jt)
#pragma unroll
    for (int mt = 0; mt < 4; ++mt) {
      aQ[jt][mt] = f32x4{0.f, 0.f, 0.f, 0.f};
      aK[jt][mt] = f32x4{0.f, 0.f, 0.f, 0.f};
    }
#pragma unroll
  for (int ks = 0; ks < 8; ++ks) {
    int off = ks * 32;
    s16x8 fq[2], fk[2];
#pragma unroll
    for (int jt = 0; jt < 2; ++jt) {
      fq[jt] = *reinterpret_cast<const s16x8*>(Wq + (size_t)jt * 4096 + off);
      fk[jt] = *reinterpret_cast<const s16x8*>(Wk + (size_t)jt * 4096 + off);
    }
    s16x8 af[4];
#pragma unroll
    for (int mt = 0; mt < 4; ++mt) {
      int row = mt * 16 + l15;
      int chunk = (ks * 4 + g) ^ (row & 7);
      af[mt] = *reinterpret_cast<const s16x8*>(smA + row * 512 + chunk * 16);
    }
    __builtin_amdgcn_s_setprio(1);
#pragma unroll
    for (int jt = 0; jt < 2; ++jt)
#pragma unroll
      for (int mt = 0; mt < 4; ++mt) {
        aQ[jt][mt] = mfma16(fq[jt], af[mt], aQ[jt][mt]);   // swapped: rows=cc
        aK[jt][mt] = mfma16(fk[jt], af[mt], aK[jt][mt]);
      }
    __builtin_amdgcn_s_setprio(0);
  }

  // pack Q,K frags (frees pass-1 AGPRs); scale folded into Q
  f32x4 bq2[2], bk2[2];
#pragma unroll
  for (int jt = 0; jt < 2; ++jt) {
    bq2[jt] = *reinterpret_cast<const f32x4*>(&bqkv[h * 32 + jt * 16 + g * 4]);
    bk2[jt] = *reinterpret_cast<const f32x4*>(&bqkv[256 + h * 32 + jt * 16 + g * 4]);
  }
  s16x8 kfr[4], qfr[4];    // lane row = 16*ti + l15, k(cc) = 16*(e>>2)+4g+(e&3)
#pragma unroll
  for (int ti = 0; ti < 4; ++ti) {
    u32x4 uk, uq;
    uk[0] = pk2(aK[0][ti][0] + bk2[0][0], aK[0][ti][1] + bk2[0][1]);
    uk[1] = pk2(aK[0][ti][2] + bk2[0][2], aK[0][ti][3] + bk2[0][3]);
    uk[2] = pk2(aK[1][ti][0] + bk2[1][0], aK[1][ti][1] + bk2[1][1]);
    uk[3] = pk2(aK[1][ti][2] + bk2[1][2], aK[1][ti][3] + bk2[1][3]);
    kfr[ti] = __builtin_bit_cast(s16x8, uk);
    uq[0] = pk2((aQ[0][ti][0] + bq2[0][0]) * scale, (aQ[0][ti][1] + bq2[0][1]) * scale);
    uq[1] = pk2((aQ[0][ti][2] + bq2[0][2]) * scale, (aQ[0][ti][3] + bq2[0][3]) * scale);
    uq[2] = pk2((aQ[1][ti][0] + bq2[1][0]) * scale, (aQ[1][ti][1] + bq2[1][1]) * scale);
    uq[3] = pk2((aQ[1][ti][2] + bq2[1][2]) * scale, (aQ[1][ti][3] + bq2[1][3]) * scale);
    qfr[ti] = __builtin_bit_cast(s16x8, uq);
  }

  // ======== pass 2: V accumulation (32 AGPR) ========
  f32x4 aV[4][2];
#pragma unroll
  for (int mt = 0; mt < 4; ++mt)
#pragma unroll
    for (int ni = 0; ni < 2; ++ni) aV[mt][ni] = f32x4{0.f, 0.f, 0.f, 0.f};
#pragma unroll
  for (int ks = 0; ks < 8; ++ks) {
    int off = ks * 32;
    s16x8 fv[2];
#pragma unroll
    for (int jt = 0; jt < 2; ++jt)
      fv[jt] = *reinterpret_cast<const s16x8*>(Wv + (size_t)jt * 4096 + off);
    s16x8 af[4];
#pragma unroll
    for (int mt = 0; mt < 4; ++mt) {
      int row = mt * 16 + l15;
      int chunk = (ks * 4 + g) ^ (row & 7);
      af[mt] = *reinterpret_cast<const s16x8*>(smA + row * 512 + chunk * 16);
    }
    __builtin_amdgcn_s_setprio(1);
#pragma unroll
    for (int mt = 0; mt < 4; ++mt)
#pragma unroll
      for (int ni = 0; ni < 2; ++ni)
        aV[mt][ni] = mfma16(af[mt], fv[ni], aV[mt][ni]);   // normal: rows=seq
    __builtin_amdgcn_s_setprio(0);
  }

  float bv2[2];
  bv2[0] = bqkv[512 + h * 32 + l15];
  bv2[1] = bqkv[512 + h * 32 + 16 + l15];
  s16x8 vfr[2][2];         // lane row = 16*ni + l15 (cc), k(t) = 16*(e>>2)+4g+(e&3)
#pragma unroll
  for (int ni = 0; ni < 2; ++ni)
#pragma unroll
    for (int ks = 0; ks < 2; ++ks) {
      u32x4 uv;
      uv[0] = pk2(aV[2 * ks][ni][0] + bv2[ni], aV[2 * ks][ni][1] + bv2[ni]);
      uv[1] = pk2(aV[2 * ks][ni][2] + bv2[ni], aV[2 * ks][ni][3] + bv2[ni]);
      uv[2] = pk2(aV[2 * ks + 1][ni][0] + bv2[ni], aV[2 * ks + 1][ni][1] + bv2[ni]);
      uv[3] = pk2(aV[2 * ks + 1][ni][2] + bv2[ni], aV[2 * ks + 1][ni][3] + bv2[ni]);
      vfr[ni][ks] = __builtin_bit_cast(s16x8, uv);
    }

  // ======== attention: exact online softmax over t-halves ========
  const float* bm = bmat + (h << 12);
  f32x4 ot[2][4];
#pragma unroll
  for (int ni = 0; ni < 2; ++ni)
#pragma unroll
    for (int si = 0; si < 4; ++si) ot[ni][si] = f32x4{0.f, 0.f, 0.f, 0.f};

  float m01[4], s01[4], inv[4];

  // ---- phase A: t in [0,32); per-si immediate (S live = 8 regs) ----
#pragma unroll
  for (int si = 0; si < 4; ++si) {
    f32x4 s0 = mfma16(kfr[0], qfr[si], f32x4{0.f, 0.f, 0.f, 0.f});
    f32x4 s1 = mfma16(kfr[1], qfr[si], f32x4{0.f, 0.f, 0.f, 0.f});
    int srow = (si * 16 + l15) * 64;
    f32x4 v0 = s0 + *reinterpret_cast<const f32x4*>(&bm[srow + g * 4]);
    f32x4 v1 = s1 + *reinterpret_cast<const f32x4*>(&bm[srow + 16 + g * 4]);
    float mx = fmaxf(fmaxf(fmaxf(v0[0], v0[1]), fmaxf(v0[2], v0[3])),
                     fmaxf(fmaxf(v1[0], v1[1]), fmaxf(v1[2], v1[3])));
    mx = fmaxf(mx, __shfl_xor(mx, 16));
    mx = fmaxf(mx, __shfl_xor(mx, 32));
    f32x4 p0, p1;
    float sum = 0.f;
#pragma unroll
    for (int r = 0; r < 4; ++r) { p0[r] = __expf(v0[r] - mx); sum += p0[r]; }
#pragma unroll
    for (int r = 0; r < 4; ++r) { p1[r] = __expf(v1[r] - mx); sum += p1[r]; }
    sum += __shfl_xor(sum, 16);
    sum += __shfl_xor(sum, 32);
    m01[si] = mx; s01[si] = sum;
    u32x4 up;
    up[0] = pk2(p0[0], p0[1]); up[1] = pk2(p0[2], p0[3]);
    up[2] = pk2(p1[0], p1[1]); up[3] = pk2(p1[2], p1[3]);
    s16x8 pf = __builtin_bit_cast(s16x8, up);
    ot[0][si] = mfma16(vfr[0][0], pf, ot[0][si]);
    ot[1][si] = mfma16(vfr[1][0], pf, ot[1][si]);
  }

  // ---- phase B: t in [32,64), exact online combine ----
#pragma unroll
  for (int si = 0; si < 4; ++si) {
    f32x4 s0 = mfma16(kfr[2], qfr[si], f32x4{0.f, 0.f, 0.f, 0.f});
    f32x4 s1 = mfma16(kfr[3], qfr[si], f32x4{0.f, 0.f, 0.f, 0.f});
    int srow = (si * 16 + l15) * 64;
    f32x4 v0 = s0 + *reinterpret_cast<const f32x4*>(&bm[srow + 32 + g * 4]);
    f32x4 v1 = s1 + *reinterpret_cast<const f32x4*>(&bm[srow + 48 + g * 4]);
    float m23 = fmaxf(fmaxf(fmaxf(v0[0], v0[1]), fmaxf(v0[2], v0[3])),
                      fmaxf(fmaxf(v1[0], v1[1]), fmaxf(v1[2], v1[3])));
    m23 = fmaxf(m23, __shfl_xor(m23, 16));
    m23 = fmaxf(m23, __shfl_xor(m23, 32));
    float m = fmaxf(m01[si], m23);
    float c01 = __expf(m01[si] - m);         // <= 1
    f32x4 p0, p1;
    float sum = 0.f;
#pragma unroll
    for (int r = 0; r < 4; ++r) { p0[r] = __expf(v0[r] - m); sum += p0[r]; }
#pragma unroll
    for (int r = 0; r < 4; ++r) { p1[r] = __expf(v1[r] - m); sum += p1[r]; }
    sum += __shfl_xor(sum, 16);
    sum += __shfl_xor(sum, 32);
    inv[si] = 1.0f / (c01 * s01[si] + sum);
    u32x4 up;
    up[0] = pk2(p0[0], p0[1]); up[1] = pk2(p0[2], p0[3]);
    up[2] = pk2(p1[0], p1[1]); up[3] = pk2(p1[2], p1[3]);
    s16x8 pf = __builtin_bit_cast(s16x8, up);
    ot[0][si] *= c01;                        // rescale phase-A contribution
    ot[1][si] *= c01;
    ot[0][si] = mfma16(vfr[0][1], pf, ot[0][si]);
    ot[1][si] = mfma16(vfr[1][1], pf, ot[1][si]);
  }

  // ======== O -> LDS (overlay dead A tile), then output projection ========
  __syncthreads();   // all waves done reading smA (pass 2)
#pragma unroll
  for (int ni = 0; ni < 2; ++ni)
#pragma unroll
    for (int si = 0; si < 4; ++si) {
      float iv = inv[si];
      int s = si * 16 + l15;
      int c0 = h * 32 + ni * 16 + g * 4;
      uint2 pk;
      pk.x = pk2(ot[ni][si][0] * iv, ot[ni][si][1] * iv);
      pk.y = pk2(ot[ni][si][2] * iv, ot[ni][si][3] * iv);
      *reinterpret_cast<uint2*>(
          smA + s * 512 + (((c0 >> 3) ^ (s & 7)) * 16) + (c0 & 7) * 2) = pk;
    }
  __syncthreads();   // O complete

  // oproj: wave w -> cols [w*32, w*32+32), K=256 from O-LDS
  f32x4 acc[4][2];
#pragma unroll
  for (int mt = 0; mt < 4; ++mt)
#pragma unroll
    for (int nt = 0; nt < 2; ++nt) acc[mt][nt] = f32x4{0.f, 0.f, 0.f, 0.f};
#pragma unroll
  for (int kk = 0; kk < 8; ++kk) {
    s16x8 bfr[2];
#pragma unroll
    for (int nt = 0; nt < 2; ++nt)
      bfr[nt] = *reinterpret_cast<const s16x8*>(
          woT + (size_t)(w * 32 + nt * 16 + l15) * 256 + kk * 32 + g * 8);
    s16x8 af[4];
#pragma unroll
    for (int mt = 0; mt < 4; ++mt) {
      int row = mt * 16 + l15;
      int chunk = (kk * 4 + g) ^ (row & 7);
      af[mt] = *reinterpret_cast<const s16x8*>(smA + row * 512 + chunk * 16);
    }
    __builtin_amdgcn_s_setprio(1);
#pragma unroll
    for (int mt = 0; mt < 4; ++mt)
#pragma unroll
      for (int nt = 0; nt < 2; ++nt)
        acc[mt][nt] = mfma16(af[mt], bfr[nt], acc[mt][nt]);
    __builtin_amdgcn_s_setprio(0);
  }

  // epilogue: +bout, un-window/un-roll, float4 fp32 stores
  int b = win >> 8, wy = (win >> 4) & 15, wx = win & 15;
#pragma unroll
  for (int nt = 0; nt < 2; ++nt) {
    int j = w * 32 + nt * 16 + l15;
    float bj = bout[j];
#pragma unroll
    for (int mt = 0; mt < 4; ++mt) {
      int seq0 = mt * 16 + g * 4;
      int iy = seq0 >> 3, ix0 = seq0 & 7;
      int y = (wy * 8 + iy + 4) & 127;
      int x0 = (wx * 8 + ix0 + 4) & 127;   // 4-aligned: float4 contiguous
      f32x4 v = acc[mt][nt];
      v.x += bj; v.y += bj; v.z += bj; v.w += bj;
      *reinterpret_cast<f32x4*>(&out[(((size_t)(b * 256 + j)) << 14) + (y << 7) + x0]) = v;
    }
  }
}

// ---------------------------------------------------------------------------
extern "C" void kernel_launch(void* const* d_in, const int* in_sizes, int n_in,
                              void* d_out, int out_size, void* d_ws, size_t ws_size,
                              hipStream_t stream) {
  const float* x    = (const float*)d_in[0];
  const float* wqkv = (const float*)d_in[1];
  const float* bqkv = (const float*)d_in[2];
  const float* wout = (const float*)d_in[3];
  const float* bout = (const float*)d_in[4];
  const float* btab = (const float*)d_in[5];
  float* out = (float*)d_out;
  char* ws = (char*)d_ws;

  unsigned short* XB = (unsigned short*)(ws);                  // 32 MB
  unsigned short* WQ = (unsigned short*)(ws + 33554432);       // 384 KB
  unsigned short* WO = (unsigned short*)(ws + 33947648);       // 128 KB
  float*          BM = (float*)(ws + 34078720);                // 128 KB
  if (ws_size < 34209792ull) return;

  k_conv_x<<<1024, 256, 0, stream>>>(x, XB);
  k_conv_w<<<1024, 256, 0, stream>>>(wqkv, wout, WQ, WO);
  k_bias<<<128, 256, 0, stream>>>(btab, BM);
  k_fused<<<1024, 512, 0, stream>>>(XB, WQ, WO, bqkv, BM, bout, out);
}

// Round 17
// 125.647 us; speedup vs baseline: 1.0155x; 1.0155x over previous
//
#include <hip/hip_runtime.h>

typedef float  f32x4  __attribute__((ext_vector_type(4)));
typedef __bf16 bf16x8 __attribute__((ext_vector_type(8)));
typedef __bf16 bf16x2 __attribute__((ext_vector_type(2)));
typedef short  s16x8  __attribute__((ext_vector_type(8)));
typedef unsigned u32x4 __attribute__((ext_vector_type(4)));

static __device__ __forceinline__ unsigned short f2bf(float f) {
  unsigned u = __builtin_bit_cast(unsigned, f);
  u += 0x7FFFu + ((u >> 16) & 1u);          // RNE
  return (unsigned short)(u >> 16);
}

// native pack: compiler emits v_cvt_pk_bf16_f32 (RNE, same numerics as f2bf)
static __device__ __forceinline__ unsigned pk2(float a, float b) {
  bf16x2 v = { (__bf16)a, (__bf16)b };
  return __builtin_bit_cast(unsigned, v);
}

static __device__ __forceinline__ f32x4 mfma16(s16x8 a, s16x8 b, f32x4 c) {
  return __builtin_amdgcn_mfma_f32_16x16x32_bf16(
      __builtin_bit_cast(bf16x8, a), __builtin_bit_cast(bf16x8, b), c, 0, 0, 0);
}

static __device__ __forceinline__ void gll16(const void* g, void* lds) {
  __builtin_amdgcn_global_load_lds(
      (const __attribute__((address_space(1))) unsigned int*)g,
      (__attribute__((address_space(3))) unsigned int*)lds, 16, 0, 0);
}

// ---------------------------------------------------------------------------
// K0: x[B,C,H,W] fp32 -> xb[m][c] bf16 (window-shifted token order),
// coalesced row reads + LDS transpose.
__global__ __launch_bounds__(256) void k_conv_x(const float* __restrict__ x,
                                                unsigned short* __restrict__ xb) {
  __shared__ __align__(16) unsigned short L[512 * 40];
  int bid = blockIdx.x;
  int cchunk = bid & 7, h2 = (bid >> 3) & 1, wy = (bid >> 4) & 15, b = bid >> 8;
  int t = threadIdx.x;
  int cpair = t >> 7, slot = t & 127, lr = slot >> 5, lp = slot & 31;
  int y = (wy * 8 + h2 * 4 + lr + 4) & 127;
  const float* row0 = x + ((size_t)b << 22) + (y << 7);
  int cbase = cchunk * 32;

  for (int it = 0; it < 8; ++it) {
    int cL0 = it * 4 + cpair * 2;
    const float* pa = row0 + ((size_t)(cbase + cL0) << 14) + lp * 4;
    f32x4 a  = *reinterpret_cast<const f32x4*>(pa);
    f32x4 c4 = *reinterpret_cast<const f32x4*>(pa + 16384);
#pragma unroll
    for (int i = 0; i < 4; ++i) {
      int xc = lp * 4 + i;
      int xp = (xc - 4) & 127;
      int wx = xp >> 3, ix = xp & 7;
      int sg = lr * 128 + ix * 16 + wx;
      unsigned pk = (unsigned)f2bf(a[i]) | ((unsigned)f2bf(c4[i]) << 16);
      *reinterpret_cast<unsigned*>(&L[sg * 40 + cL0]) = pk;
    }
  }
  __syncthreads();

  size_t M0 = ((size_t)((b * 16 + wy) * 16)) * 64 + h2 * 32;
  for (int pass = 0; pass < 8; ++pass) {
    int tk = pass * 64 + (t >> 2), p = t & 3;
    int wx = tk >> 5, lr2 = (tk >> 3) & 3, ix = tk & 7;
    int sg = lr2 * 128 + ix * 16 + wx;
    uint4 v = *reinterpret_cast<const uint4*>(&L[sg * 40 + p * 8]);
    size_t m = M0 + (size_t)wx * 64 + lr2 * 8 + ix;
    *reinterpret_cast<uint4*>(&xb[m * 256 + cbase + p * 8]) = v;
  }
}

// ---------------------------------------------------------------------------
// K0b: weight transposes -> K-minor bf16.
__global__ __launch_bounds__(256) void k_conv_w(const float* __restrict__ wqkv,
                                                const float* __restrict__ wout,
                                                unsigned short* __restrict__ wqkvT,
                                                unsigned short* __restrict__ woutT) {
  int j = blockIdx.x, c = threadIdx.x;
  if (j < 768) wqkvT[j * 256 + c] = f2bf(wqkv[c * 768 + j]);
  else { int jj = j - 768; woutT[jj * 256 + c] = f2bf(wout[c * 256 + jj]); }
}

// ---------------------------------------------------------------------------
// K0c: expand relative-position bias table -> bmat[h][s][t] f32 (128 KB).
__global__ __launch_bounds__(256) void k_bias(const float* __restrict__ btab,
                                              float* __restrict__ bmat) {
  int i = blockIdx.x * 256 + threadIdx.x;   // [h][s][t]
  int t = i & 63, s = (i >> 6) & 63, h = i >> 12;
  int idx = ((s >> 3) - (t >> 3) + 7) * 15 + ((s & 7) - (t & 7) + 7);
  bmat[i] = btab[idx * 8 + h];
}

// ---------------------------------------------------------------------------
// K1 fused (FINAL, R10/R15 configuration — measured best 125.7 us total):
// QKV projection + attention + output projection, one block per window
// (8 waves = 8 heads, 512 threads). 32 KB LDS holds A, then O (overlay).
// launch_bounds(512,4): 2 blocks/CU. Occupancy/register knob fully sampled
// (512,2)/(512,3)/(512,4) -> k_fused 112/111/111 us; this config is the
// measured optimum. Latency-bound structural plateau: MfmaUtil ~14%,
// HBM ~13%, every sampled structure within +/-8% of this floor.
__global__ __launch_bounds__(512, 4) void k_fused(const unsigned short* __restrict__ xb,
                                                  const unsigned short* __restrict__ wT,
                                                  const unsigned short* __restrict__ woT,
                                                  const float* __restrict__ bqkv,
                                                  const float* __restrict__ bmat,
                                                  const float* __restrict__ bout,
                                                  float* __restrict__ out) {
  __shared__ __align__(16) unsigned char smA[32768];
  int lane = threadIdx.x & 63, w = threadIdx.x >> 6;
  int bid = blockIdx.x;
  int win = (bid & 7) * 128 + (bid >> 3);   // XCD-bijective swizzle (1024 % 8 == 0)
  int h = w;
  int g = lane >> 4, l15 = lane & 15;
  int m0 = win * 64;
  const float scale = 0.17677669529663687f; // 1/sqrt(32)

  // ---- stage A (64 rows x 256 cols bf16) to LDS, 4 gll16 per wave ----
#pragma unroll
  for (int i = 0; i < 4; ++i) {
    int inst = w * 4 + i;                    // wave-uniform 0..31
    int row = inst * 2 + (lane >> 5);
    int sg = (lane & 31) ^ (row & 7);
    gll16(xb + (size_t)(m0 + row) * 256 + sg * 8, smA + inst * 1024);
  }
  __syncthreads();

  const unsigned short* Wq = wT + (size_t)(h * 32 + l15) * 256 + g * 8;
  const unsigned short* Wk = Wq + 65536;    // +256 rows
  const unsigned short* Wv = Wk + 65536;

  // ======== pass 1: Q,K accumulation (64 AGPR) ========
  f32x4 aQ[2][4], aK[2][4];
#pragma unroll
  for (int jt = 0; jt < 2; ++jt)
#pragma unroll
    for (int mt = 0; mt < 4; ++mt) {
      aQ[jt][mt] = f32x4{0.f, 0.f, 0.f, 0.f};
      aK[jt][mt] = f32x4{0.f, 0.f, 0.f, 0.f};
    }
#pragma unroll
  for (int ks = 0; ks < 8; ++ks) {
    int off = ks * 32;
    s16x8 fq[2], fk[2];
#pragma unroll
    for (int jt = 0; jt < 2; ++jt) {
      fq[jt] = *reinterpret_cast<const s16x8*>(Wq + (size_t)jt * 4096 + off);
      fk[jt] = *reinterpret_cast<const s16x8*>(Wk + (size_t)jt * 4096 + off);
    }
    s16x8 af[4];
#pragma unroll
    for (int mt = 0; mt < 4; ++mt) {
      int row = mt * 16 + l15;
      int chunk = (ks * 4 + g) ^ (row & 7);
      af[mt] = *reinterpret_cast<const s16x8*>(smA + row * 512 + chunk * 16);
    }
    __builtin_amdgcn_s_setprio(1);
#pragma unroll
    for (int jt = 0; jt < 2; ++jt)
#pragma unroll
      for (int mt = 0; mt < 4; ++mt) {
        aQ[jt][mt] = mfma16(fq[jt], af[mt], aQ[jt][mt]);   // swapped: rows=cc
        aK[jt][mt] = mfma16(fk[jt], af[mt], aK[jt][mt]);
      }
    __builtin_amdgcn_s_setprio(0);
  }

  // pack Q,K frags (frees pass-1 AGPRs); scale folded into Q
  f32x4 bq2[2], bk2[2];
#pragma unroll
  for (int jt = 0; jt < 2; ++jt) {
    bq2[jt] = *reinterpret_cast<const f32x4*>(&bqkv[h * 32 + jt * 16 + g * 4]);
    bk2[jt] = *reinterpret_cast<const f32x4*>(&bqkv[256 + h * 32 + jt * 16 + g * 4]);
  }
  s16x8 kfr[4], qfr[4];    // lane row = 16*ti + l15, k(cc) = 16*(e>>2)+4g+(e&3)
#pragma unroll
  for (int ti = 0; ti < 4; ++ti) {
    u32x4 uk, uq;
    uk[0] = pk2(aK[0][ti][0] + bk2[0][0], aK[0][ti][1] + bk2[0][1]);
    uk[1] = pk2(aK[0][ti][2] + bk2[0][2], aK[0][ti][3] + bk2[0][3]);
    uk[2] = pk2(aK[1][ti][0] + bk2[1][0], aK[1][ti][1] + bk2[1][1]);
    uk[3] = pk2(aK[1][ti][2] + bk2[1][2], aK[1][ti][3] + bk2[1][3]);
    kfr[ti] = __builtin_bit_cast(s16x8, uk);
    uq[0] = pk2((aQ[0][ti][0] + bq2[0][0]) * scale, (aQ[0][ti][1] + bq2[0][1]) * scale);
    uq[1] = pk2((aQ[0][ti][2] + bq2[0][2]) * scale, (aQ[0][ti][3] + bq2[0][3]) * scale);
    uq[2] = pk2((aQ[1][ti][0] + bq2[1][0]) * scale, (aQ[1][ti][1] + bq2[1][1]) * scale);
    uq[3] = pk2((aQ[1][ti][2] + bq2[1][2]) * scale, (aQ[1][ti][3] + bq2[1][3]) * scale);
    qfr[ti] = __builtin_bit_cast(s16x8, uq);
  }

  // ======== pass 2: V accumulation (32 AGPR) ========
  f32x4 aV[4][2];
#pragma unroll
  for (int mt = 0; mt < 4; ++mt)
#pragma unroll
    for (int ni = 0; ni < 2; ++ni) aV[mt][ni] = f32x4{0.f, 0.f, 0.f, 0.f};
#pragma unroll
  for (int ks = 0; ks < 8; ++ks) {
    int off = ks * 32;
    s16x8 fv[2];
#pragma unroll
    for (int jt = 0; jt < 2; ++jt)
      fv[jt] = *reinterpret_cast<const s16x8*>(Wv + (size_t)jt * 4096 + off);
    s16x8 af[4];
#pragma unroll
    for (int mt = 0; mt < 4; ++mt) {
      int row = mt * 16 + l15;
      int chunk = (ks * 4 + g) ^ (row & 7);
      af[mt] = *reinterpret_cast<const s16x8*>(smA + row * 512 + chunk * 16);
    }
    __builtin_amdgcn_s_setprio(1);
#pragma unroll
    for (int mt = 0; mt < 4; ++mt)
#pragma unroll
      for (int ni = 0; ni < 2; ++ni)
        aV[mt][ni] = mfma16(af[mt], fv[ni], aV[mt][ni]);   // normal: rows=seq
    __builtin_amdgcn_s_setprio(0);
  }

  float bv2[2];
  bv2[0] = bqkv[512 + h * 32 + l15];
  bv2[1] = bqkv[512 + h * 32 + 16 + l15];
  s16x8 vfr[2][2];         // lane row = 16*ni + l15 (cc), k(t) = 16*(e>>2)+4g+(e&3)
#pragma unroll
  for (int ni = 0; ni < 2; ++ni)
#pragma unroll
    for (int ks = 0; ks < 2; ++ks) {
      u32x4 uv;
      uv[0] = pk2(aV[2 * ks][ni][0] + bv2[ni], aV[2 * ks][ni][1] + bv2[ni]);
      uv[1] = pk2(aV[2 * ks][ni][2] + bv2[ni], aV[2 * ks][ni][3] + bv2[ni]);
      uv[2] = pk2(aV[2 * ks + 1][ni][0] + bv2[ni], aV[2 * ks + 1][ni][1] + bv2[ni]);
      uv[3] = pk2(aV[2 * ks + 1][ni][2] + bv2[ni], aV[2 * ks + 1][ni][3] + bv2[ni]);
      vfr[ni][ks] = __builtin_bit_cast(s16x8, uv);
    }

  // ======== attention: exact online softmax over t-halves ========
  const float* bm = bmat + (h << 12);
  f32x4 ot[2][4];
#pragma unroll
  for (int ni = 0; ni < 2; ++ni)
#pragma unroll
    for (int si = 0; si < 4; ++si) ot[ni][si] = f32x4{0.f, 0.f, 0.f, 0.f};

  float m01[4], s01[4], inv[4];

  // ---- phase A: t in [0,32); per-si immediate (S live = 8 regs) ----
#pragma unroll
  for (int si = 0; si < 4; ++si) {
    f32x4 s0 = mfma16(kfr[0], qfr[si], f32x4{0.f, 0.f, 0.f, 0.f});
    f32x4 s1 = mfma16(kfr[1], qfr[si], f32x4{0.f, 0.f, 0.f, 0.f});
    int srow = (si * 16 + l15) * 64;
    f32x4 v0 = s0 + *reinterpret_cast<const f32x4*>(&bm[srow + g * 4]);
    f32x4 v1 = s1 + *reinterpret_cast<const f32x4*>(&bm[srow + 16 + g * 4]);
    float mx = fmaxf(fmaxf(fmaxf(v0[0], v0[1]), fmaxf(v0[2], v0[3])),
                     fmaxf(fmaxf(v1[0], v1[1]), fmaxf(v1[2], v1[3])));
    mx = fmaxf(mx, __shfl_xor(mx, 16));
    mx = fmaxf(mx, __shfl_xor(mx, 32));
    f32x4 p0, p1;
    float sum = 0.f;
#pragma unroll
    for (int r = 0; r < 4; ++r) { p0[r] = __expf(v0[r] - mx); sum += p0[r]; }
#pragma unroll
    for (int r = 0; r < 4; ++r) { p1[r] = __expf(v1[r] - mx); sum += p1[r]; }
    sum += __shfl_xor(sum, 16);
    sum += __shfl_xor(sum, 32);
    m01[si] = mx; s01[si] = sum;
    u32x4 up;
    up[0] = pk2(p0[0], p0[1]); up[1] = pk2(p0[2], p0[3]);
    up[2] = pk2(p1[0], p1[1]); up[3] = pk2(p1[2], p1[3]);
    s16x8 pf = __builtin_bit_cast(s16x8, up);
    ot[0][si] = mfma16(vfr[0][0], pf, ot[0][si]);
    ot[1][si] = mfma16(vfr[1][0], pf, ot[1][si]);
  }

  // ---- phase B: t in [32,64), exact online combine ----
#pragma unroll
  for (int si = 0; si < 4; ++si) {
    f32x4 s0 = mfma16(kfr[2], qfr[si], f32x4{0.f, 0.f, 0.f, 0.f});
    f32x4 s1 = mfma16(kfr[3], qfr[si], f32x4{0.f, 0.f, 0.f, 0.f});
    int srow = (si * 16 + l15) * 64;
    f32x4 v0 = s0 + *reinterpret_cast<const f32x4*>(&bm[srow + 32 + g * 4]);
    f32x4 v1 = s1 + *reinterpret_cast<const f32x4*>(&bm[srow + 48 + g * 4]);
    float m23 = fmaxf(fmaxf(fmaxf(v0[0], v0[1]), fmaxf(v0[2], v0[3])),
                      fmaxf(fmaxf(v1[0], v1[1]), fmaxf(v1[2], v1[3])));
    m23 = fmaxf(m23, __shfl_xor(m23, 16));
    m23 = fmaxf(m23, __shfl_xor(m23, 32));
    float m = fmaxf(m01[si], m23);
    float c01 = __expf(m01[si] - m);         // <= 1
    f32x4 p0, p1;
    float sum = 0.f;
#pragma unroll
    for (int r = 0; r < 4; ++r) { p0[r] = __expf(v0[r] - m); sum += p0[r]; }
#pragma unroll
    for (int r = 0; r < 4; ++r) { p1[r] = __expf(v1[r] - m); sum += p1[r]; }
    sum += __shfl_xor(sum, 16);
    sum += __shfl_xor(sum, 32);
    inv[si] = 1.0f / (c01 * s01[si] + sum);
    u32x4 up;
    up[0] = pk2(p0[0], p0[1]); up[1] = pk2(p0[2], p0[3]);
    up[2] = pk2(p1[0], p1[1]); up[3] = pk2(p1[2], p1[3]);
    s16x8 pf = __builtin_bit_cast(s16x8, up);
    ot[0][si] *= c01;                        // rescale phase-A contribution
    ot[1][si] *= c01;
    ot[0][si] = mfma16(vfr[0][1], pf, ot[0][si]);
    ot[1][si] = mfma16(vfr[1][1], pf, ot[1][si]);
  }

  // ======== O -> LDS (overlay dead A tile), then output projection ========
  __syncthreads();   // all waves done reading smA (pass 2)
#pragma unroll
  for (int ni = 0; ni < 2; ++ni)
#pragma unroll
    for (int si = 0; si < 4; ++si) {
      float iv = inv[si];
      int s = si * 16 + l15;
      int c0 = h * 32 + ni * 16 + g * 4;
      uint2 pk;
      pk.x = pk2(ot[ni][si][0] * iv, ot[ni][si][1] * iv);
      pk.y = pk2(ot[ni][si][2] * iv, ot[ni][si][3] * iv);
      *reinterpret_cast<uint2*>(
          smA + s * 512 + (((c0 >> 3) ^ (s & 7)) * 16) + (c0 & 7) * 2) = pk;
    }
  __syncthreads();   // O complete

  // oproj: wave w -> cols [w*32, w*32+32), K=256 from O-LDS
  f32x4 acc[4][2];
#pragma unroll
  for (int mt = 0; mt < 4; ++mt)
#pragma unroll
    for (int nt = 0; nt < 2; ++nt) acc[mt][nt] = f32x4{0.f, 0.f, 0.f, 0.f};
#pragma unroll
  for (int kk = 0; kk < 8; ++kk) {
    s16x8 bfr[2];
#pragma unroll
    for (int nt = 0; nt < 2; ++nt)
      bfr[nt] = *reinterpret_cast<const s16x8*>(
          woT + (size_t)(w * 32 + nt * 16 + l15) * 256 + kk * 32 + g * 8);
    s16x8 af[4];
#pragma unroll
    for (int mt = 0; mt < 4; ++mt) {
      int row = mt * 16 + l15;
      int chunk = (kk * 4 + g) ^ (row & 7);
      af[mt] = *reinterpret_cast<const s16x8*>(smA + row * 512 + chunk * 16);
    }
    __builtin_amdgcn_s_setprio(1);
#pragma unroll
    for (int mt = 0; mt < 4; ++mt)
#pragma unroll
      for (int nt = 0; nt < 2; ++nt)
        acc[mt][nt] = mfma16(af[mt], bfr[nt], acc[mt][nt]);
    __builtin_amdgcn_s_setprio(0);
  }

  // epilogue: +bout, un-window/un-roll, float4 fp32 stores
  int b = win >> 8, wy = (win >> 4) & 15, wx = win & 15;
#pragma unroll
  for (int nt = 0; nt < 2; ++nt) {
    int j = w * 32 + nt * 16 + l15;
    float bj = bout[j];
#pragma unroll
    for (int mt = 0; mt < 4; ++mt) {
      int seq0 = mt * 16 + g * 4;
      int iy = seq0 >> 3, ix0 = seq0 & 7;
      int y = (wy * 8 + iy + 4) & 127;
      int x0 = (wx * 8 + ix0 + 4) & 127;   // 4-aligned: float4 contiguous
      f32x4 v = acc[mt][nt];
      v.x += bj; v.y += bj; v.z += bj; v.w += bj;
      *reinterpret_cast<f32x4*>(&out[(((size_t)(b * 256 + j)) << 14) + (y << 7) + x0]) = v;
    }
  }
}

// ---------------------------------------------------------------------------
extern "C" void kernel_launch(void* const* d_in, const int* in_sizes, int n_in,
                              void* d_out, int out_size, void* d_ws, size_t ws_size,
                              hipStream_t stream) {
  const float* x    = (const float*)d_in[0];
  const float* wqkv = (const float*)d_in[1];
  const float* bqkv = (const float*)d_in[2];
  const float* wout = (const float*)d_in[3];
  const float* bout = (const float*)d_in[4];
  const float* btab = (const float*)d_in[5];
  float* out = (float*)d_out;
  char* ws = (char*)d_ws;

  unsigned short* XB = (unsigned short*)(ws);                  // 32 MB
  unsigned short* WQ = (unsigned short*)(ws + 33554432);       // 384 KB
  unsigned short* WO = (unsigned short*)(ws + 33947648);       // 128 KB
  float*          BM = (float*)(ws + 34078720);                // 128 KB
  if (ws_size < 34209792ull) return;

  k_conv_x<<<1024, 256, 0, stream>>>(x, XB);
  k_conv_w<<<1024, 256, 0, stream>>>(wqkv, wout, WQ, WO);
  k_bias<<<128, 256, 0, stream>>>(btab, BM);
  k_fused<<<1024, 512, 0, stream>>>(XB, WQ, WO, bqkv, BM, bout, out);
}